// Round 5
// baseline (257.087 us; speedup 1.0000x reference)
//
#include <hip/hip_runtime.h>
#include <hip/hip_bf16.h>
#include <cstdint>
#include <cstddef>

#define BATCH 32
#define CIN   256
#define COUT  256
#define HH    56
#define WW    56
#define HP    60      // padded rows: 0..57 read; 58/59 slack (zeroed)
#define WPAD  64      // padded cols: 0,57 are conv zero-pad; 58..63 slack (zeroed)
#define KTOT  2304    // 9 * 256
#define NT    72      // K-tiles of 32

typedef __attribute__((ext_vector_type(4)))  float f32x4;
typedef __attribute__((ext_vector_type(16))) float f32x16;
typedef __attribute__((ext_vector_type(8)))  short short8;

// ---------------- zero only the padding cells of xq (12.4 MB, not 63 MB) ----------------
__global__ void zeropad_kernel(unsigned short* __restrict__ xq)
{
    const int b   = blockIdx.y;
    const int idx = blockIdx.x * 256 + threadIdx.x;   // 0..22527
    const int pos = idx >> 5;
    const int ch  = (idx & 31) * 8;
    int hp, wp;
    if (pos < 256) {                     // rows {0,57,58,59} full
        int r = pos >> 6;
        hp = (r == 0) ? 0 : 56 + r;
        wp = pos & 63;
    } else {                             // rows 1..56, cols {0,57..63}
        int i2 = pos - 256;
        int c  = i2 & 7;
        hp = (i2 >> 3) + 1;
        wp = (c == 0) ? 0 : 56 + c;
    }
    short8 z = {0, 0, 0, 0, 0, 0, 0, 0};
    *reinterpret_cast<short8*>(xq + (((size_t)b * HP + hp) * WPAD + wp) * CIN + ch) = z;
}

// ---------------- BFP quantize + NCHW->padded-NHWC bf16 repack ----------------
__global__ void quant_kernel(const float* __restrict__ x, unsigned short* __restrict__ xq)
{
    const int h   = blockIdx.x;       // 0..55
    const int b   = blockIdx.y;       // 0..31
    const int tid = threadIdx.x;
    const int wv  = tid >> 6;
    const int w   = tid & 63;
    if (w >= WW) return;
    for (int cb = wv; cb < 8; cb += 4) {
        float v[32];
        float mx = 0.f;
        const float* xp = x + (((size_t)b * CIN + cb * 32) * HH + h) * WW + w;
#pragma unroll
        for (int c = 0; c < 32; ++c) {
            float t = xp[(size_t)c * HH * WW];
            v[c] = t;
            mx = fmaxf(mx, fabsf(t));
        }
        float m = fmaxf(mx, 1e-12f);
        int e;
        frexpf(m, &e);
        e -= 1;                                  // exact floor(log2(m))
        e = (e < -64) ? -64 : ((e > 63) ? 63 : e);
        float step = exp2f((float)(e - 7));
        float inv  = exp2f((float)(7 - e));
        unsigned short qb[32];
#pragma unroll
        for (int c = 0; c < 32; ++c) {
            float q = rintf(v[c] * inv);          // round-half-even, matches jnp.round
            q = fminf(fmaxf(q, -128.f), 127.f);
            float val = q * step;                 // exactly representable in bf16
            __hip_bfloat16 bv = __float2bfloat16(val);
            qb[c] = *reinterpret_cast<unsigned short*>(&bv);
        }
        unsigned short* dst = xq + (((size_t)b * HP + (h + 1)) * WPAD + (w + 1)) * CIN + cb * 32;
#pragma unroll
        for (int i = 0; i < 4; ++i)
            *reinterpret_cast<short8*>(dst + i * 8) = *reinterpret_cast<const short8*>(qb + i * 8);
    }
}

// ---------------- weight repack: OIHW fp32 -> [n][j=kh*3+kw][c] bf16 ----------------
__global__ void wrepack_kernel(const float* __restrict__ Wsrc, unsigned short* __restrict__ Wr)
{
    int idx = blockIdx.x * 256 + threadIdx.x;
    if (idx >= COUT * KTOT) return;
    int n = idx / KTOT;
    int r = idx % KTOT;
    int j = r >> 8;    // 0..8
    int c = r & 255;
    float val = Wsrc[((size_t)n * CIN + c) * 9 + j];
    __hip_bfloat16 bv = __float2bfloat16(val);
    Wr[idx] = *reinterpret_cast<unsigned short*>(&bv);
}

// ---------------- implicit-GEMM conv: 256x256 tile, 4 waves x (128x128), 32x32x16 MFMA ----
// Rationale: LDS-read BW is the structural floor (per K-32: sum over waves of
// (m_w+n_w)*64B). 4 fat waves (128x128 each) -> 64 KB/CU/K-tile vs 96 KB with
// 8 thin waves. acc = 16 x f32x16 (AGPR), 1 wave/SIMD.
//
// LDS fragment-order layout per 16 KB buffer: elem ((g*2+kk)*64 + l)*8
//   g = 32-row group (0..7), kk = k-half (0..1), l = lane; lane l reads its
//   16B at byte l*16 within each 1 KB fragment -> conflict-free ds_read_b128,
//   all frag/buf selectors are compile-time immediate offsets.
// A-frag for v_mfma_f32_32x32x16_bf16: lane l -> (row=l&31, k=(l>>5)*8+e)
// (analog of the verified 16x16x32 mapping). C/D: col=lane&31,
// row=(r&3)+8*(r>>2)+4*(lane>>5)  [HW-verified].
__device__ __forceinline__ void gload_lds16(const void* g, void* l)
{
    __builtin_amdgcn_global_load_lds((const __attribute__((address_space(1))) void*)g,
                                     (__attribute__((address_space(3))) void*)l, 16, 0, 0);
}

#define SCB() __builtin_amdgcn_sched_barrier(0)
#define BAR() do { SCB(); __builtin_amdgcn_s_barrier(); SCB(); } while (0)
#define VMWAIT(n) do { asm volatile("s_waitcnt vmcnt(" #n ")" ::: "memory"); } while (0)

// One K-32 iter: 16 ds_read_b128 (frags) + 8 global_load_lds (tile t+3) +
// 32 MFMA(32x32x16) + counted VMWAIT + ONE barrier.
//   WAR: stage writes buf (t+3)&3=(t-1)&3, last read in iter t-1 (pre-barrier).
//   RAW: VMWAIT(16) at end of iter t-1 drains the 8 loads of tile t.
#define KSTEP(CB, OA, OB, STG, VMT) do {                                                  \
    const unsigned short* Ac = As + ((CB) & 3) * 8192;                                    \
    const unsigned short* Bc = Bs + ((CB) & 3) * 8192;                                    \
    short8 av[2][4], bv[2][4];                                                            \
    _Pragma("unroll")                                                                     \
    for (int kk = 0; kk < 2; ++kk)                                                        \
        _Pragma("unroll")                                                                 \
        for (int f = 0; f < 4; ++f)                                                       \
            av[kk][f] = *(const short8*)(Ac + ardB + f * 1024 + kk * 512);                \
    _Pragma("unroll")                                                                     \
    for (int kk = 0; kk < 2; ++kk)                                                        \
        _Pragma("unroll")                                                                 \
        for (int e = 0; e < 4; ++e)                                                       \
            bv[kk][e] = *(const short8*)(Bc + brdB + e * 1024 + kk * 512);                \
    if (STG) { stgA(((CB) + 3) & 3, (OA)); stgB(((CB) + 3) & 3, (OB)); }                  \
    _Pragma("unroll")                                                                     \
    for (int kk = 0; kk < 2; ++kk)                                                        \
        _Pragma("unroll")                                                                 \
        for (int f = 0; f < 4; ++f)                                                       \
            _Pragma("unroll")                                                             \
            for (int e = 0; e < 4; ++e)                                                   \
                acc[f][e] = __builtin_amdgcn_mfma_f32_32x32x16_bf16(av[kk][f], bv[kk][e], \
                                                                    acc[f][e], 0, 0, 0);  \
    VMT;                                                                                  \
    BAR();                                                                                \
} while (0)

__global__ __launch_bounds__(256, 1) void conv_gemm_kernel(const unsigned short* __restrict__ xq,
                                                           const unsigned short* __restrict__ Wr,
                                                           float* __restrict__ out,
                                                           float* __restrict__ sums)
{
    extern __shared__ __align__(16) unsigned short lds[];
    unsigned short* As = lds;            // 4 bufs x 8192 shorts (64 KB)
    unsigned short* Bs = lds + 32768;    // 4 bufs x 8192 shorts (64 KB)

    const int bid  = blockIdx.x;                    // 0..447
    const int blk  = (bid & 7) * 56 + (bid >> 3);   // bijective XCD swizzle (448 = 8*56)
    const int b    = blk / 14;
    const int m0   = (blk % 14) * 256;
    const int tid  = threadIdx.x;
    const int wv   = tid >> 6;          // 0..3
    const int lane = tid & 63;
    const int l31  = lane & 31;
    const int l5   = lane >> 5;
    const int wm   = wv >> 1;           // 0..1
    const int wn   = wv & 1;            // 0..1

    const unsigned short* Ab = xq + (size_t)b * (HP * WPAD * CIN);

    // ds-read element bases: + f*1024 + kk*512 (+ buf*8192) all immediate
    const int ardB = wm * 4096 + lane * 8;
    const int brdB = wn * 4096 + lane * 8;

    // staging decomposition: per q, dest elem e=q*256+tid -> (g,kk,l);
    // source row = g*32+(l&31), k-in-tile = kk*16+(l>>5)*8  (pre-swizzled)
    size_t abase[4], bbase[4];
    int    dstE[4];
#pragma unroll
    for (int q = 0; q < 4; ++q) {
        int e  = q * 256 + tid;
        int g  = e >> 7, kk = (e >> 6) & 1, ll = e & 63;
        int row = g * 32 + (ll & 31);
        int kc  = kk * 16 + (ll >> 5) * 8;
        abase[q] = (size_t)(m0 + row) * CIN + kc;
        bbase[q] = (size_t)row * KTOT + kc;
        dstE[q]  = e * 8;
    }
    auto stgA = [&](int buf, int off) {
#pragma unroll
        for (int q = 0; q < 4; ++q)
            gload_lds16(Ab + abase[q] + off, (void*)(As + buf * 8192 + dstE[q]));
    };
    auto stgB = [&](int buf, int off) {
#pragma unroll
        for (int q = 0; q < 4; ++q)
            gload_lds16(Wr + bbase[q] + off, (void*)(Bs + buf * 8192 + dstE[q]));
    };

    f32x16 acc[4][4];
#pragma unroll
    for (int f = 0; f < 4; ++f)
#pragma unroll
        for (int e = 0; e < 4; ++e)
#pragma unroll
            for (int r = 0; r < 16; ++r) acc[f][e][r] = 0.f;

    // prologue: stage tiles 0,1,2 (tap j=0, cb=0..2)
    stgA(0, 0);  stgB(0, 0);
    stgA(1, 32); stgB(1, 32);
    stgA(2, 64); stgB(2, 64);
    VMWAIT(16);
    BAR();

    // K-loop: t = j*8+cb; buffer = cb&3 (compile-time); stage tile t+3:
    //   cb<=4 -> (j, cb+3); cb>=5 -> (j+1, cb-5)
    int oA0 = 0, oA1 = 256, jmod = 1;   // oA0=tap(j), oA1=tap(j+1), jmod=(j+1)%3
    for (int j = 0; j < 8; ++j) {
        const int oB0 = j * 256, oB1 = oB0 + 256;
        KSTEP(0, oA0 + 96,  oB0 + 96,  true, VMWAIT(16));
        KSTEP(1, oA0 + 128, oB0 + 128, true, VMWAIT(16));
        KSTEP(2, oA0 + 160, oB0 + 160, true, VMWAIT(16));
        KSTEP(3, oA0 + 192, oB0 + 192, true, VMWAIT(16));
        KSTEP(4, oA0 + 224, oB0 + 224, true, VMWAIT(16));
        KSTEP(5, oA1 + 0,   oB1 + 0,   true, VMWAIT(16));
        KSTEP(6, oA1 + 32,  oB1 + 32,  true, VMWAIT(16));
        KSTEP(7, oA1 + 64,  oB1 + 64,  true, VMWAIT(16));
        oA0 = oA1;
        oA1 += (jmod == 2) ? 15872 : 256;   // tap(j+2)-tap(j+1)
        jmod = (jmod == 2) ? 0 : jmod + 1;
    }
    { // j = 8 (taps: oA0 = tap(8); oA1 unused for staging here)
        const int oB0 = 2048;
        KSTEP(0, oA0 + 96,  oB0 + 96,  true,  VMWAIT(16));
        KSTEP(1, oA0 + 128, oB0 + 128, true,  VMWAIT(16));
        KSTEP(2, oA0 + 160, oB0 + 160, true,  VMWAIT(16));
        KSTEP(3, oA0 + 192, oB0 + 192, true,  VMWAIT(16));
        KSTEP(4, oA0 + 224, oB0 + 224, true,  VMWAIT(16));
        KSTEP(5, 0, 0, false, VMWAIT(8));
        KSTEP(6, 0, 0, false, VMWAIT(0));
        KSTEP(7, 0, 0, false, (void)0);
    }

    // epilogue: per frag reg r: n = wn*128+ni*32+(lane&31),
    // m = m0+wm*128+mi*32+8*(r>>2)+4*(lane>>5)+(r&3) -> f32x4 stores.
    // w>=56 padding quads are exactly (mi odd && q==3). Fused BN stats.
#pragma unroll
    for (int ni = 0; ni < 4; ++ni) {
        const int n = wn * 128 + ni * 32 + l31;
        float s = 0.f, s2 = 0.f;
#pragma unroll
        for (int mi = 0; mi < 4; ++mi) {
#pragma unroll
            for (int q = 0; q < 4; ++q) {
                if ((mi & 1) && q == 3) continue;     // w = 56/60: padding
                const int m = m0 + wm * 128 + mi * 32 + q * 8 + l5 * 4;
                const int h = m >> 6, w = m & 63;
                f32x4 v = { acc[mi][ni][q * 4 + 0], acc[mi][ni][q * 4 + 1],
                            acc[mi][ni][q * 4 + 2], acc[mi][ni][q * 4 + 3] };
                s  += v[0] + v[1] + v[2] + v[3];
                s2 += v[0] * v[0] + v[1] * v[1] + v[2] * v[2] + v[3] * v[3];
                *reinterpret_cast<f32x4*>(&out[(((size_t)b * COUT + n) * HH + h) * WW + w]) = v;
            }
        }
        s  += __shfl_xor(s, 32);
        s2 += __shfl_xor(s2, 32);
        if (l5 == 0) {
            atomicAdd(&sums[n], s);
            atomicAdd(&sums[COUT + n], s2);
        }
    }
}

// ---------------- BN normalize + affine + ReLU (in place, f32x4) ----------------
__global__ void bn_apply_kernel(float* __restrict__ y, const float* __restrict__ sums,
                                const float* __restrict__ gamma, const float* __restrict__ beta)
{
    const int o = blockIdx.x, b = blockIdx.y;
    const float N = (float)(BATCH * HH * WW);
    const float mean = sums[o] / N;
    const float var  = sums[COUT + o] / N - mean * mean;
    const float inv  = 1.f / sqrtf(var + 1e-5f);
    const float a  = gamma[o] * inv;
    const float bb = beta[o] - mean * a;
    float* p = y + ((size_t)b * COUT + o) * (HH * WW);
    for (int i = threadIdx.x; i < 784; i += 256) {
        f32x4 v = *reinterpret_cast<const f32x4*>(p + i * 4);
#pragma unroll
        for (int r = 0; r < 4; ++r) v[r] = fmaxf(v[r] * a + bb, 0.f);
        *reinterpret_cast<f32x4*>(p + i * 4) = v;
    }
}

extern "C" void kernel_launch(void* const* d_in, const int* in_sizes, int n_in,
                              void* d_out, int out_size, void* d_ws, size_t ws_size,
                              hipStream_t stream)
{
    const float* x     = (const float*)d_in[0];
    const float* Wsrc  = (const float*)d_in[1];
    const float* gamma = (const float*)d_in[2];
    const float* beta  = (const float*)d_in[3];
    float* out = (float*)d_out;

    char* ws = (char*)d_ws;
    const size_t XQ_BYTES = (size_t)BATCH * HP * WPAD * CIN * 2;  // 62,914,560
    const size_t WR_BYTES = (size_t)COUT * KTOT * 2;              //  1,179,648
    unsigned short* xq = (unsigned short*)ws;
    unsigned short* wr = (unsigned short*)(ws + XQ_BYTES);
    float* sums = (float*)(ws + XQ_BYTES + WR_BYTES);

    hipMemsetAsync(sums, 0, 2 * COUT * sizeof(float), stream);

    zeropad_kernel<<<dim3(88, BATCH), 256, 0, stream>>>(xq);
    quant_kernel<<<dim3(HH, BATCH), 256, 0, stream>>>(x, xq);
    wrepack_kernel<<<(COUT * KTOT + 255) / 256, 256, 0, stream>>>(Wsrc, wr);

    hipFuncSetAttribute(reinterpret_cast<const void*>(&conv_gemm_kernel),
                        hipFuncAttributeMaxDynamicSharedMemorySize, 131072);
    conv_gemm_kernel<<<448, 256, 131072, stream>>>(xq, wr, out, sums);

    bn_apply_kernel<<<dim3(COUT, BATCH), 256, 0, stream>>>(out, sums, gamma, beta);
}